// Round 10
// baseline (97.704 us; speedup 1.0000x reference)
//
#include <hip/hip_runtime.h>
#include <hip/hip_bf16.h>

// LocalPPM: B=4, C=256, H=W=56, R=2 (5x5 -> K2=25), TOPK=10, TAU=0.1, EPS=1e-8
// out = x + gamma * sum_k softmax_top10(cos_sim(center, neighbor_k)/TAU) * neighbor_k
//
// Symmetry: dot(p, +o) == dot(p+o, -o); only 13 offsets k=0..12 computed.
// SINGLE regular kernel with a software grid barrier between phase A
// (dot planes -> ws) and phase B (sims -> top-10 softmax -> output).
// Barrier counter is hipMemsetAsync'd to 0 before every launch (replay-safe).
// Co-residency: 392 blocks; LDS 33KB -> 4 blk/CU, launch_bounds(512,4)
// caps VGPR<=128 -> >=2 blk/CU -> capacity >=512 > 392. No deadlock.

#define PX 3136   // 56*56
#define CS 3136   // channel plane stride (H*W)
#define NBLK 392u

typedef float f4a __attribute__((ext_vector_type(4), aligned(4)));

// block 512 = 32 px x 16 ch-chunks (16 ch each); grid (98, 4).
__global__ __launch_bounds__(512, 4) void k_all(const float* __restrict__ x,
                                                float* __restrict__ dot,
                                                unsigned* __restrict__ ctr,
                                                const float* __restrict__ gptr,
                                                float* __restrict__ out) {
    const int tid = threadIdx.x;
    const int b   = blockIdx.y;

    __shared__ float part[16][13][32];             // 26.6 KB (phase A)
    __shared__ float s_lds[32][25];                // phase B
    __shared__ float e_lds[32][25];
    __shared__ float inv_lds[32];

    // ================= phase A: 13 dot planes =================
    {
        const int px = tid & 31;
        const int ck = tid >> 5;                   // 0..15 channel chunk (16 ch)
        const int p  = blockIdx.x * 32 + px;
        const int h  = p / 56;
        const int w  = p - h * 56;

        const bool vm2 = (h >= 2), vm1 = (h >= 1);
        const bool cv0 = (w >= 2), cv1 = (w >= 1), cv3 = (w <= 54), cv4 = (w <= 53);

        const float* xb  = x + (size_t)b * 256 * CS + (size_t)ck * 16 * CS;
        const float* cp  = xb + p;        // center (row h, col w)
        const float* pr2 = cp - 112;      // row h-2
        const float* pr1 = cp - 56;       // row h-1

        float a[13];
        #pragma unroll
        for (int i = 0; i < 13; ++i) a[i] = 0.f;

        // c == 0: masked scalar path (low tensor corner safety)
        {
            const float ctrv = cp[0];
            float n;
            n = (vm2 && cv0) ? pr2[-2] : 0.f; a[0]  = fmaf(ctrv, n, a[0]);
            n = (vm2 && cv1) ? pr2[-1] : 0.f; a[1]  = fmaf(ctrv, n, a[1]);
            n =  vm2         ? pr2[ 0] : 0.f; a[2]  = fmaf(ctrv, n, a[2]);
            n = (vm2 && cv3) ? pr2[ 1] : 0.f; a[3]  = fmaf(ctrv, n, a[3]);
            n = (vm2 && cv4) ? pr2[ 2] : 0.f; a[4]  = fmaf(ctrv, n, a[4]);
            n = (vm1 && cv0) ? pr1[-2] : 0.f; a[5]  = fmaf(ctrv, n, a[5]);
            n = (vm1 && cv1) ? pr1[-1] : 0.f; a[6]  = fmaf(ctrv, n, a[6]);
            n =  vm1         ? pr1[ 0] : 0.f; a[7]  = fmaf(ctrv, n, a[7]);
            n = (vm1 && cv3) ? pr1[ 1] : 0.f; a[8]  = fmaf(ctrv, n, a[8]);
            n = (vm1 && cv4) ? pr1[ 2] : 0.f; a[9]  = fmaf(ctrv, n, a[9]);
            n =  cv0         ? cp [-2] : 0.f; a[10] = fmaf(ctrv, n, a[10]);
            n =  cv1         ? cp [-1] : 0.f; a[11] = fmaf(ctrv, n, a[11]);
            a[12] = fmaf(ctrv, ctrv, a[12]);
        }

        const bool tail_unsafe = (b == 3) && (ck == 15);   // high tensor corner

        // c = 1..15: UNCONDITIONAL loads + FMA (garbage for out-of-image taps
        // lands in dot entries phase B never reads).
        #pragma unroll 5
        for (int c = 1; c < 16; ++c) {
            const int o = c * CS;
            if (c == 15 && tail_unsafe) {
                const f4a   t2  = *(const f4a*)(pr2 + o - 2);
                const float t2e = pr2[o + 2];
                const f4a   t1  = *(const f4a*)(pr1 + o - 2);
                const float t1e = pr1[o + 2];
                const float c0  = cp[o - 2], c1 = cp[o - 1], ctrv = cp[o];
                a[0]  = fmaf(ctrv, t2.x, a[0]);
                a[1]  = fmaf(ctrv, t2.y, a[1]);
                a[2]  = fmaf(ctrv, t2.z, a[2]);
                a[3]  = fmaf(ctrv, t2.w, a[3]);
                a[4]  = fmaf(ctrv, t2e,  a[4]);
                a[5]  = fmaf(ctrv, t1.x, a[5]);
                a[6]  = fmaf(ctrv, t1.y, a[6]);
                a[7]  = fmaf(ctrv, t1.z, a[7]);
                a[8]  = fmaf(ctrv, t1.w, a[8]);
                a[9]  = fmaf(ctrv, t1e,  a[9]);
                a[10] = fmaf(ctrv, c0,   a[10]);
                a[11] = fmaf(ctrv, c1,   a[11]);
                a[12] = fmaf(ctrv, ctrv, a[12]);
            } else {
                const f4a   t2  = *(const f4a*)(pr2 + o - 2);
                const float t2e = pr2[o + 2];
                const f4a   t1  = *(const f4a*)(pr1 + o - 2);
                const float t1e = pr1[o + 2];
                const f4a   t0  = *(const f4a*)(cp  + o - 2);
                const float ctrv = t0.z;
                a[0]  = fmaf(ctrv, t2.x, a[0]);
                a[1]  = fmaf(ctrv, t2.y, a[1]);
                a[2]  = fmaf(ctrv, t2.z, a[2]);
                a[3]  = fmaf(ctrv, t2.w, a[3]);
                a[4]  = fmaf(ctrv, t2e,  a[4]);
                a[5]  = fmaf(ctrv, t1.x, a[5]);
                a[6]  = fmaf(ctrv, t1.y, a[6]);
                a[7]  = fmaf(ctrv, t1.z, a[7]);
                a[8]  = fmaf(ctrv, t1.w, a[8]);
                a[9]  = fmaf(ctrv, t1e,  a[9]);
                a[10] = fmaf(ctrv, t0.x, a[10]);
                a[11] = fmaf(ctrv, t0.y, a[11]);
                a[12] = fmaf(ctrv, ctrv, a[12]);
            }
        }

        #pragma unroll
        for (int i = 0; i < 13; ++i) part[ck][i][px] = a[i];
        __syncthreads();

        if (tid < 13 * 32) {
            const int acc = tid >> 5, pp = tid & 31;
            float s = 0.f;
            #pragma unroll
            for (int j = 0; j < 16; ++j) s += part[j][acc][pp];
            dot[((size_t)(b * 13 + acc)) * PX + blockIdx.x * 32 + pp] = s;
        }
    }

    // ================= software grid barrier =================
    __syncthreads();
    if (tid == 0) {
        __threadfence();                           // publish my dot writes
        atomicAdd(ctr, 1u);                        // device-scope
        while (__hip_atomic_load(ctr, __ATOMIC_ACQUIRE,
                                 __HIP_MEMORY_SCOPE_AGENT) < NBLK) {
            __builtin_amdgcn_s_sleep(1);
        }
        __threadfence();                           // see others' dot writes
    }
    __syncthreads();

    // ================= phase B: sims -> top-10 softmax -> output =================
    const int pbase = blockIdx.x * 32;
    const float* db = dot + (size_t)b * 13 * PX;

    // ---- B1: sims into LDS (validity-masked; garbage dot never read) ----
    #pragma unroll
    for (int i = tid; i < 800; i += 512) {
        const int px = i / 25, k = i - px * 25;
        const int p = pbase + px;
        const int h = p / 56, w = p - (p / 56) * 56;
        const int dy = k / 5 - 2, dx = k % 5 - 2;
        const int rr = h + dy, cc = w + dx;
        const bool v = (rr >= 0) && (rr < 56) && (cc >= 0) && (cc < 56);
        float d = 0.f, n2 = 0.f;
        if (v) {
            const int q = rr * 56 + cc;
            n2 = db[12 * PX + q];
            d  = (k <= 12) ? db[k * PX + p] : db[(24 - k) * PX + q];
        }
        const float cn = sqrtf(db[12 * PX + p]);
        s_lds[px][k] = d / fmaxf(sqrtf(n2) * cn, 1e-8f) * 10.f;
    }
    __syncthreads();

    // ---- B2: rank (exact top-10, JAX tie-break) + max + exp ----
    #pragma unroll
    for (int i = tid; i < 800; i += 512) {
        const int px = i / 25, k = i - px * 25;
        const float sk = s_lds[px][k];
        int rank = 0;
        float m = sk;
        #pragma unroll
        for (int j = 0; j < 25; ++j) {
            const float sj = s_lds[px][j];
            rank += (int)((sj > sk) || ((sj == sk) && (j < k)));
            m = fmaxf(m, sj);
        }
        e_lds[px][k] = (rank < 10) ? __expf(sk - m) : 0.f;
    }
    __syncthreads();

    // ---- B3: per-pixel denom ----
    if (tid < 32) {
        float denom = 0.f;
        #pragma unroll
        for (int k = 0; k < 25; ++k) denom += e_lds[tid][k];
        inv_lds[tid] = 1.f / denom;
    }
    __syncthreads();

    // ---- B4: weighted accumulation over channels ----
    const int px  = tid & 31;
    const int sub = tid >> 5;                      // 0..15, 16 channels each
    const int p   = pbase + px;
    const int h   = p / 56;
    const int w   = p - h * 56;
    const float g = *gptr;

    const bool vm2 = (h >= 2), vm1 = (h >= 1), vp1 = (h <= 54), vp2 = (h <= 53);
    const bool cv0 = (w >= 2), cv1 = (w >= 1), cv3 = (w <= 54), cv4 = (w <= 53);

    // pre-masked weights: invalid tap => weight 0 (its neighbor is the zero
    // vector in the reference, so contribution is 0 regardless of weight)
    const float inv = inv_lds[px];
    float wq[25];
    #pragma unroll
    for (int k = 0; k < 25; ++k) {
        const int dy = k / 5 - 2, dx = k % 5 - 2;
        const bool vr = (dy == -2) ? vm2 : (dy == -1) ? vm1 : (dy == 0) ? true
                      : (dy == 1) ? vp1 : vp2;
        const bool vc = (dx == -2) ? cv0 : (dx == -1) ? cv1 : (dx == 0) ? true
                      : (dx == 1) ? cv3 : cv4;
        wq[k] = (vr && vc) ? e_lds[px][k] * inv : 0.f;
    }

    const float* xb = x   + ((size_t)b * 256 + sub * 16) * CS;
    float*       ob = out + ((size_t)b * 256 + sub * 16) * CS;

    #pragma unroll 2
    for (int ci = 0; ci < 16; ++ci) {
        const float* xp = xb + ci * CS + p;
        const bool unsafe = (b == 0 && sub == 0 && ci == 0) ||
                            (b == 3 && sub == 15 && ci == 15);
        float y = 0.f, ctrv;
        if (!unsafe) {
            #pragma unroll
            for (int r = 0; r < 5; ++r) {
                const float* rp = xp + (r - 2) * 56;
                const f4a   v4 = *(const f4a*)(rp - 2);    // dx -2..+1
                const float s4 = rp[2];                    // dx +2
                if (r == 2) ctrv = v4.z;
                y = fmaf(wq[r*5+0], v4.x, y);
                y = fmaf(wq[r*5+1], v4.y, y);
                y = fmaf(wq[r*5+2], v4.z, y);
                y = fmaf(wq[r*5+3], v4.w, y);
                y = fmaf(wq[r*5+4], s4,   y);
            }
        } else {
            ctrv = xp[0];
            #pragma unroll
            for (int k = 0; k < 25; ++k) {
                const int dy = k / 5 - 2, dx = k % 5 - 2;
                const bool vr = (dy == -2) ? vm2 : (dy == -1) ? vm1 : (dy == 0) ? true
                              : (dy == 1) ? vp1 : vp2;
                const bool vc = (dx == -2) ? cv0 : (dx == -1) ? cv1 : (dx == 0) ? true
                              : (dx == 1) ? cv3 : cv4;
                const float xv = (vr && vc) ? xp[dy * 56 + dx] : 0.f;
                y = fmaf(wq[k], xv, y);
            }
        }
        ob[ci * CS + p] = ctrv + g * y;
    }
}

extern "C" void kernel_launch(void* const* d_in, const int* in_sizes, int n_in,
                              void* d_out, int out_size, void* d_ws, size_t ws_size,
                              hipStream_t stream) {
    const float* x     = (const float*)d_in[0];
    const float* gamma = (const float*)d_in[1];
    float* out = (float*)d_out;
    float* dot = (float*)d_ws;                       // [4][13][3136] floats
    unsigned* ctr = (unsigned*)((char*)d_ws + 4u * 13u * PX * sizeof(float));

    hipMemsetAsync(ctr, 0, sizeof(unsigned), stream);    // replay-safe barrier
    k_all<<<dim3(98, 4), 512, 0, stream>>>(x, dot, ctr, gamma, out);
}

// Round 11
// 33.184 us; speedup vs baseline: 2.9443x; 2.9443x over previous
//
#include <hip/hip_runtime.h>
#include <hip/hip_bf16.h>

// LocalPPM: B=4, C=256, H=W=56, R=2 (5x5 -> K2=25), TOPK=10, TAU=0.1, EPS=1e-8
// out = x + gamma * sum_k softmax_top10(cos_sim(center, neighbor_k)/TAU) * neighbor_k
//
// Symmetry: dot(p, +o) == dot(p+o, -o); only 13 offsets k=0..12 computed.
// R10: two kernels (R7 bodies) + XCD-slab swizzle. With the bid%8 XCD
// round-robin dispatch heuristic, decode bid so each XCD owns a contiguous
// (batch, half-image) slab (~1.7 MB < 4 MB per-XCD L2): x fetched from HBM
// ~once per kernel instead of 3-5x (R9 profile: 88 MB fetch, 13% BW).

#define PX 3136   // 56*56
#define CS 3136   // channel plane stride (H*W)

typedef float f4a __attribute__((ext_vector_type(4), aligned(4)));

// xcd = bid&7 owns batch b = xcd>>1, image-half = xcd&1 (49 strips of 32 px).
#define DECODE_SLAB()                                   \
    const int bid   = blockIdx.x;                       \
    const int xcd   = bid & 7;                          \
    const int b     = xcd >> 1;                         \
    const int pbase = (((xcd & 1) * 49) + (bid >> 3)) * 32;

// block 512 = 32 px x 16 ch-chunks (16 ch each); grid 392.
__global__ __launch_bounds__(512) void k_dot(const float* __restrict__ x,
                                             float* __restrict__ dot) {
    DECODE_SLAB();
    const int px = threadIdx.x & 31;
    const int ck = threadIdx.x >> 5;               // 0..15 channel chunk (16 ch)
    const int p  = pbase + px;
    const int h  = p / 56;
    const int w  = p - h * 56;

    const bool vm2 = (h >= 2), vm1 = (h >= 1);
    const bool cv0 = (w >= 2), cv1 = (w >= 1), cv3 = (w <= 54), cv4 = (w <= 53);

    const float* xb  = x + (size_t)b * 256 * CS + (size_t)ck * 16 * CS;
    const float* cp  = xb + p;        // center (row h, col w)
    const float* pr2 = cp - 112;      // row h-2
    const float* pr1 = cp - 56;       // row h-1

    float a[13];
    #pragma unroll
    for (int i = 0; i < 13; ++i) a[i] = 0.f;

    // c == 0: masked scalar path (low tensor corner safety)
    {
        const float ctr = cp[0];
        float n;
        n = (vm2 && cv0) ? pr2[-2] : 0.f; a[0]  = fmaf(ctr, n, a[0]);
        n = (vm2 && cv1) ? pr2[-1] : 0.f; a[1]  = fmaf(ctr, n, a[1]);
        n =  vm2         ? pr2[ 0] : 0.f; a[2]  = fmaf(ctr, n, a[2]);
        n = (vm2 && cv3) ? pr2[ 1] : 0.f; a[3]  = fmaf(ctr, n, a[3]);
        n = (vm2 && cv4) ? pr2[ 2] : 0.f; a[4]  = fmaf(ctr, n, a[4]);
        n = (vm1 && cv0) ? pr1[-2] : 0.f; a[5]  = fmaf(ctr, n, a[5]);
        n = (vm1 && cv1) ? pr1[-1] : 0.f; a[6]  = fmaf(ctr, n, a[6]);
        n =  vm1         ? pr1[ 0] : 0.f; a[7]  = fmaf(ctr, n, a[7]);
        n = (vm1 && cv3) ? pr1[ 1] : 0.f; a[8]  = fmaf(ctr, n, a[8]);
        n = (vm1 && cv4) ? pr1[ 2] : 0.f; a[9]  = fmaf(ctr, n, a[9]);
        n =  cv0         ? cp [-2] : 0.f; a[10] = fmaf(ctr, n, a[10]);
        n =  cv1         ? cp [-1] : 0.f; a[11] = fmaf(ctr, n, a[11]);
        a[12] = fmaf(ctr, ctr, a[12]);
    }

    const bool tail_unsafe = (b == 3) && (ck == 15);   // high tensor corner

    // c = 1..15: UNCONDITIONAL loads + FMA (garbage for out-of-image taps
    // lands in dot entries k_fused never reads).
    #pragma unroll 5
    for (int c = 1; c < 16; ++c) {
        const int o = c * CS;
        if (c == 15 && tail_unsafe) {
            const f4a   t2  = *(const f4a*)(pr2 + o - 2);
            const float t2e = pr2[o + 2];
            const f4a   t1  = *(const f4a*)(pr1 + o - 2);
            const float t1e = pr1[o + 2];
            const float c0  = cp[o - 2], c1 = cp[o - 1], ctr = cp[o];
            a[0]  = fmaf(ctr, t2.x, a[0]);
            a[1]  = fmaf(ctr, t2.y, a[1]);
            a[2]  = fmaf(ctr, t2.z, a[2]);
            a[3]  = fmaf(ctr, t2.w, a[3]);
            a[4]  = fmaf(ctr, t2e,  a[4]);
            a[5]  = fmaf(ctr, t1.x, a[5]);
            a[6]  = fmaf(ctr, t1.y, a[6]);
            a[7]  = fmaf(ctr, t1.z, a[7]);
            a[8]  = fmaf(ctr, t1.w, a[8]);
            a[9]  = fmaf(ctr, t1e,  a[9]);
            a[10] = fmaf(ctr, c0,   a[10]);
            a[11] = fmaf(ctr, c1,   a[11]);
            a[12] = fmaf(ctr, ctr,  a[12]);
        } else {
            const f4a   t2  = *(const f4a*)(pr2 + o - 2);   // row h-2, dx -2..+1
            const float t2e = pr2[o + 2];
            const f4a   t1  = *(const f4a*)(pr1 + o - 2);   // row h-1
            const float t1e = pr1[o + 2];
            const f4a   t0  = *(const f4a*)(cp  + o - 2);   // row h, dx -2..+1
            const float ctr = t0.z;
            a[0]  = fmaf(ctr, t2.x, a[0]);
            a[1]  = fmaf(ctr, t2.y, a[1]);
            a[2]  = fmaf(ctr, t2.z, a[2]);
            a[3]  = fmaf(ctr, t2.w, a[3]);
            a[4]  = fmaf(ctr, t2e,  a[4]);
            a[5]  = fmaf(ctr, t1.x, a[5]);
            a[6]  = fmaf(ctr, t1.y, a[6]);
            a[7]  = fmaf(ctr, t1.z, a[7]);
            a[8]  = fmaf(ctr, t1.w, a[8]);
            a[9]  = fmaf(ctr, t1e,  a[9]);
            a[10] = fmaf(ctr, t0.x, a[10]);
            a[11] = fmaf(ctr, t0.y, a[11]);
            a[12] = fmaf(ctr, ctr,  a[12]);
        }
    }

    __shared__ float part[16][13][32];             // 26.6 KB
    #pragma unroll
    for (int i = 0; i < 13; ++i) part[ck][i][px] = a[i];
    __syncthreads();

    if (threadIdx.x < 13 * 32) {
        const int acc = threadIdx.x >> 5, pp = threadIdx.x & 31;
        float s = 0.f;
        #pragma unroll
        for (int j = 0; j < 16; ++j) s += part[j][acc][pp];
        dot[((size_t)(b * 13 + acc)) * PX + pbase + pp] = s;
    }
}

// Fused weights + output. block 512 = 32 px x 16 ch-subgroups (16 ch each).
// grid 392, same slab decode.
__global__ __launch_bounds__(512) void k_fused(const float* __restrict__ x,
                                               const float* __restrict__ dot,
                                               const float* __restrict__ gptr,
                                               float* __restrict__ out) {
    DECODE_SLAB();
    const int tid = threadIdx.x;
    const float* db = dot + (size_t)b * 13 * PX;

    __shared__ float s_lds[32][25];
    __shared__ float e_lds[32][25];
    __shared__ float inv_lds[32];

    // ---- phase 1a: sims into LDS (validity-masked; garbage dot never read) ----
    #pragma unroll
    for (int i = tid; i < 800; i += 512) {
        const int px = i / 25, k = i - px * 25;
        const int p = pbase + px;
        const int h = p / 56, w = p - (p / 56) * 56;
        const int dy = k / 5 - 2, dx = k % 5 - 2;
        const int rr = h + dy, cc = w + dx;
        const bool v = (rr >= 0) && (rr < 56) && (cc >= 0) && (cc < 56);
        float d = 0.f, n2 = 0.f;
        if (v) {
            const int q = rr * 56 + cc;
            n2 = db[12 * PX + q];
            d  = (k <= 12) ? db[k * PX + p] : db[(24 - k) * PX + q];
        }
        const float cn = sqrtf(db[12 * PX + p]);
        s_lds[px][k] = d / fmaxf(sqrtf(n2) * cn, 1e-8f) * 10.f;
    }
    __syncthreads();

    // ---- phase 1b: rank (exact top-10, JAX tie-break) + max + exp ----
    #pragma unroll
    for (int i = tid; i < 800; i += 512) {
        const int px = i / 25, k = i - px * 25;
        const float sk = s_lds[px][k];
        int rank = 0;
        float m = sk;
        #pragma unroll
        for (int j = 0; j < 25; ++j) {
            const float sj = s_lds[px][j];
            rank += (int)((sj > sk) || ((sj == sk) && (j < k)));
            m = fmaxf(m, sj);
        }
        e_lds[px][k] = (rank < 10) ? __expf(sk - m) : 0.f;
    }
    __syncthreads();

    // ---- phase 1c: per-pixel denom ----
    if (tid < 32) {
        float denom = 0.f;
        #pragma unroll
        for (int k = 0; k < 25; ++k) denom += e_lds[tid][k];
        inv_lds[tid] = 1.f / denom;
    }
    __syncthreads();

    // ---- phase 2: weighted accumulation over channels ----
    const int px  = tid & 31;
    const int sub = tid >> 5;                      // 0..15, 16 channels each
    const int p   = pbase + px;
    const int h   = p / 56;
    const int w   = p - h * 56;
    const float g = *gptr;

    const bool vm2 = (h >= 2), vm1 = (h >= 1), vp1 = (h <= 54), vp2 = (h <= 53);
    const bool cv0 = (w >= 2), cv1 = (w >= 1), cv3 = (w <= 54), cv4 = (w <= 53);

    // pre-masked weights: invalid tap => weight 0 (its neighbor is the zero
    // vector in the reference, so contribution is 0 regardless of weight)
    const float inv = inv_lds[px];
    float wq[25];
    #pragma unroll
    for (int k = 0; k < 25; ++k) {
        const int dy = k / 5 - 2, dx = k % 5 - 2;
        const bool vr = (dy == -2) ? vm2 : (dy == -1) ? vm1 : (dy == 0) ? true
                      : (dy == 1) ? vp1 : vp2;
        const bool vc = (dx == -2) ? cv0 : (dx == -1) ? cv1 : (dx == 0) ? true
                      : (dx == 1) ? cv3 : cv4;
        wq[k] = (vr && vc) ? e_lds[px][k] * inv : 0.f;
    }

    const float* xb = x   + ((size_t)b * 256 + sub * 16) * CS;
    float*       ob = out + ((size_t)b * 256 + sub * 16) * CS;

    #pragma unroll 2
    for (int ci = 0; ci < 16; ++ci) {
        const float* xp = xb + ci * CS + p;
        const bool unsafe = (b == 0 && sub == 0 && ci == 0) ||
                            (b == 3 && sub == 15 && ci == 15);
        float y = 0.f, ctr;
        if (!unsafe) {
            #pragma unroll
            for (int r = 0; r < 5; ++r) {
                const float* rp = xp + (r - 2) * 56;
                const f4a   v4 = *(const f4a*)(rp - 2);    // dx -2..+1
                const float s4 = rp[2];                    // dx +2
                if (r == 2) ctr = v4.z;
                y = fmaf(wq[r*5+0], v4.x, y);
                y = fmaf(wq[r*5+1], v4.y, y);
                y = fmaf(wq[r*5+2], v4.z, y);
                y = fmaf(wq[r*5+3], v4.w, y);
                y = fmaf(wq[r*5+4], s4,   y);
            }
        } else {
            ctr = xp[0];
            #pragma unroll
            for (int k = 0; k < 25; ++k) {
                const int dy = k / 5 - 2, dx = k % 5 - 2;
                const bool vr = (dy == -2) ? vm2 : (dy == -1) ? vm1 : (dy == 0) ? true
                              : (dy == 1) ? vp1 : vp2;
                const bool vc = (dx == -2) ? cv0 : (dx == -1) ? cv1 : (dx == 0) ? true
                              : (dx == 1) ? cv3 : cv4;
                const float xv = (vr && vc) ? xp[dy * 56 + dx] : 0.f;
                y = fmaf(wq[k], xv, y);
            }
        }
        ob[ci * CS + p] = ctr + g * y;
    }
}

extern "C" void kernel_launch(void* const* d_in, const int* in_sizes, int n_in,
                              void* d_out, int out_size, void* d_ws, size_t ws_size,
                              hipStream_t stream) {
    const float* x     = (const float*)d_in[0];
    const float* gamma = (const float*)d_in[1];
    float* out = (float*)d_out;
    float* dot = (float*)d_ws;                 // [4][13][3136]

    k_dot<<<392, 512, 0, stream>>>(x, dot);
    k_fused<<<392, 512, 0, stream>>>(x, dot, gamma, out);
}

// Round 12
// 32.529 us; speedup vs baseline: 3.0036x; 1.0201x over previous
//
#include <hip/hip_runtime.h>
#include <hip/hip_bf16.h>

// LocalPPM: B=4, C=256, H=W=56, R=2 (5x5 -> K2=25), TOPK=10, TAU=0.1, EPS=1e-8
// out = x + gamma * sum_k softmax_top10(cos_sim(center, neighbor_k)/TAU) * neighbor_k
//
// Symmetry: dot(p, +o) == dot(p+o, -o); only 13 offsets k=0..12 computed.
// R11 = R10 (XCD-slab swizzle, proven +7us) + 1024-thread blocks:
// 32 px (coalescing unit) x 32 ch-chunks (8 ch) -> 6 waves/SIMD (2x R10)
// to cover ~200cy L2-hit latency. R4/R5 occupancy tests were confounded
// (pre-swizzle cache-thrash regime); this retests in the latency regime.

#define PX 3136   // 56*56
#define CS 3136   // channel plane stride (H*W)

typedef float f4a __attribute__((ext_vector_type(4), aligned(4)));

// xcd = bid&7 owns batch b = xcd>>1, image-half = xcd&1 (49 strips of 32 px).
#define DECODE_SLAB()                                   \
    const int bid   = blockIdx.x;                       \
    const int xcd   = bid & 7;                          \
    const int b     = xcd >> 1;                         \
    const int pbase = (((xcd & 1) * 49) + (bid >> 3)) * 32;

// block 1024 = 32 px x 32 ch-chunks (8 ch each); grid 392.
__global__ __launch_bounds__(1024) void k_dot(const float* __restrict__ x,
                                              float* __restrict__ dot) {
    DECODE_SLAB();
    const int px = threadIdx.x & 31;
    const int ck = threadIdx.x >> 5;               // 0..31 channel chunk (8 ch)
    const int p  = pbase + px;
    const int h  = p / 56;
    const int w  = p - h * 56;

    const bool vm2 = (h >= 2), vm1 = (h >= 1);
    const bool cv0 = (w >= 2), cv1 = (w >= 1), cv3 = (w <= 54), cv4 = (w <= 53);

    const float* xb  = x + (size_t)b * 256 * CS + (size_t)ck * 8 * CS;
    const float* cp  = xb + p;        // center (row h, col w)
    const float* pr2 = cp - 112;      // row h-2
    const float* pr1 = cp - 56;       // row h-1

    float a[13];
    #pragma unroll
    for (int i = 0; i < 13; ++i) a[i] = 0.f;

    // c == 0: masked scalar path (low tensor corner safety)
    {
        const float ctr = cp[0];
        float n;
        n = (vm2 && cv0) ? pr2[-2] : 0.f; a[0]  = fmaf(ctr, n, a[0]);
        n = (vm2 && cv1) ? pr2[-1] : 0.f; a[1]  = fmaf(ctr, n, a[1]);
        n =  vm2         ? pr2[ 0] : 0.f; a[2]  = fmaf(ctr, n, a[2]);
        n = (vm2 && cv3) ? pr2[ 1] : 0.f; a[3]  = fmaf(ctr, n, a[3]);
        n = (vm2 && cv4) ? pr2[ 2] : 0.f; a[4]  = fmaf(ctr, n, a[4]);
        n = (vm1 && cv0) ? pr1[-2] : 0.f; a[5]  = fmaf(ctr, n, a[5]);
        n = (vm1 && cv1) ? pr1[-1] : 0.f; a[6]  = fmaf(ctr, n, a[6]);
        n =  vm1         ? pr1[ 0] : 0.f; a[7]  = fmaf(ctr, n, a[7]);
        n = (vm1 && cv3) ? pr1[ 1] : 0.f; a[8]  = fmaf(ctr, n, a[8]);
        n = (vm1 && cv4) ? pr1[ 2] : 0.f; a[9]  = fmaf(ctr, n, a[9]);
        n =  cv0         ? cp [-2] : 0.f; a[10] = fmaf(ctr, n, a[10]);
        n =  cv1         ? cp [-1] : 0.f; a[11] = fmaf(ctr, n, a[11]);
        a[12] = fmaf(ctr, ctr, a[12]);
    }

    const bool tail_unsafe = (b == 3) && (ck == 31);   // high tensor corner

    // c = 1..7: UNCONDITIONAL loads + FMA (garbage for out-of-image taps
    // lands in dot entries k_fused never reads).
    #pragma unroll
    for (int c = 1; c < 8; ++c) {
        const int o = c * CS;
        if (c == 7 && tail_unsafe) {
            const f4a   t2  = *(const f4a*)(pr2 + o - 2);
            const float t2e = pr2[o + 2];
            const f4a   t1  = *(const f4a*)(pr1 + o - 2);
            const float t1e = pr1[o + 2];
            const float c0  = cp[o - 2], c1 = cp[o - 1], ctr = cp[o];
            a[0]  = fmaf(ctr, t2.x, a[0]);
            a[1]  = fmaf(ctr, t2.y, a[1]);
            a[2]  = fmaf(ctr, t2.z, a[2]);
            a[3]  = fmaf(ctr, t2.w, a[3]);
            a[4]  = fmaf(ctr, t2e,  a[4]);
            a[5]  = fmaf(ctr, t1.x, a[5]);
            a[6]  = fmaf(ctr, t1.y, a[6]);
            a[7]  = fmaf(ctr, t1.z, a[7]);
            a[8]  = fmaf(ctr, t1.w, a[8]);
            a[9]  = fmaf(ctr, t1e,  a[9]);
            a[10] = fmaf(ctr, c0,   a[10]);
            a[11] = fmaf(ctr, c1,   a[11]);
            a[12] = fmaf(ctr, ctr,  a[12]);
        } else {
            const f4a   t2  = *(const f4a*)(pr2 + o - 2);   // row h-2, dx -2..+1
            const float t2e = pr2[o + 2];
            const f4a   t1  = *(const f4a*)(pr1 + o - 2);   // row h-1
            const float t1e = pr1[o + 2];
            const f4a   t0  = *(const f4a*)(cp  + o - 2);   // row h, dx -2..+1
            const float ctr = t0.z;
            a[0]  = fmaf(ctr, t2.x, a[0]);
            a[1]  = fmaf(ctr, t2.y, a[1]);
            a[2]  = fmaf(ctr, t2.z, a[2]);
            a[3]  = fmaf(ctr, t2.w, a[3]);
            a[4]  = fmaf(ctr, t2e,  a[4]);
            a[5]  = fmaf(ctr, t1.x, a[5]);
            a[6]  = fmaf(ctr, t1.y, a[6]);
            a[7]  = fmaf(ctr, t1.z, a[7]);
            a[8]  = fmaf(ctr, t1.w, a[8]);
            a[9]  = fmaf(ctr, t1e,  a[9]);
            a[10] = fmaf(ctr, t0.x, a[10]);
            a[11] = fmaf(ctr, t0.y, a[11]);
            a[12] = fmaf(ctr, ctr,  a[12]);
        }
    }

    __shared__ float part[32][13][32];             // 53.2 KB
    #pragma unroll
    for (int i = 0; i < 13; ++i) part[ck][i][px] = a[i];
    __syncthreads();

    if (threadIdx.x < 13 * 32) {
        const int acc = threadIdx.x >> 5, pp = threadIdx.x & 31;
        float s = 0.f;
        #pragma unroll
        for (int j = 0; j < 32; ++j) s += part[j][acc][pp];
        dot[((size_t)(b * 13 + acc)) * PX + pbase + pp] = s;
    }
}

// Fused weights + output. block 1024 = 32 px x 32 ch-subgroups (8 ch each).
// grid 392, same slab decode.
__global__ __launch_bounds__(1024) void k_fused(const float* __restrict__ x,
                                                const float* __restrict__ dot,
                                                const float* __restrict__ gptr,
                                                float* __restrict__ out) {
    DECODE_SLAB();
    const int tid = threadIdx.x;
    const float* db = dot + (size_t)b * 13 * PX;

    __shared__ float s_lds[32][25];
    __shared__ float e_lds[32][25];
    __shared__ float inv_lds[32];

    // ---- phase 1a: sims into LDS (800 items, single shot) ----
    if (tid < 800) {
        const int px = tid / 25, k = tid - (tid / 25) * 25;
        const int p = pbase + px;
        const int h = p / 56, w = p - (p / 56) * 56;
        const int dy = k / 5 - 2, dx = k % 5 - 2;
        const int rr = h + dy, cc = w + dx;
        const bool v = (rr >= 0) && (rr < 56) && (cc >= 0) && (cc < 56);
        float d = 0.f, n2 = 0.f;
        if (v) {
            const int q = rr * 56 + cc;
            n2 = db[12 * PX + q];
            d  = (k <= 12) ? db[k * PX + p] : db[(24 - k) * PX + q];
        }
        const float cn = sqrtf(db[12 * PX + p]);
        s_lds[px][k] = d / fmaxf(sqrtf(n2) * cn, 1e-8f) * 10.f;
    }
    __syncthreads();

    // ---- phase 1b: rank (exact top-10, JAX tie-break) + max + exp ----
    if (tid < 800) {
        const int px = tid / 25, k = tid - (tid / 25) * 25;
        const float sk = s_lds[px][k];
        int rank = 0;
        float m = sk;
        #pragma unroll
        for (int j = 0; j < 25; ++j) {
            const float sj = s_lds[px][j];
            rank += (int)((sj > sk) || ((sj == sk) && (j < k)));
            m = fmaxf(m, sj);
        }
        e_lds[px][k] = (rank < 10) ? __expf(sk - m) : 0.f;
    }
    __syncthreads();

    // ---- phase 1c: per-pixel denom ----
    if (tid < 32) {
        float denom = 0.f;
        #pragma unroll
        for (int k = 0; k < 25; ++k) denom += e_lds[tid][k];
        inv_lds[tid] = 1.f / denom;
    }
    __syncthreads();

    // ---- phase 2: weighted accumulation over channels ----
    const int px  = tid & 31;
    const int sub = tid >> 5;                      // 0..31, 8 channels each
    const int p   = pbase + px;
    const int h   = p / 56;
    const int w   = p - h * 56;
    const float g = *gptr;

    const bool vm2 = (h >= 2), vm1 = (h >= 1), vp1 = (h <= 54), vp2 = (h <= 53);
    const bool cv0 = (w >= 2), cv1 = (w >= 1), cv3 = (w <= 54), cv4 = (w <= 53);

    // pre-masked weights: invalid tap => weight 0 (its neighbor is the zero
    // vector in the reference, so contribution is 0 regardless of weight)
    const float inv = inv_lds[px];
    float wq[25];
    #pragma unroll
    for (int k = 0; k < 25; ++k) {
        const int dy = k / 5 - 2, dx = k % 5 - 2;
        const bool vr = (dy == -2) ? vm2 : (dy == -1) ? vm1 : (dy == 0) ? true
                      : (dy == 1) ? vp1 : vp2;
        const bool vc = (dx == -2) ? cv0 : (dx == -1) ? cv1 : (dx == 0) ? true
                      : (dx == 1) ? cv3 : cv4;
        wq[k] = (vr && vc) ? e_lds[px][k] * inv : 0.f;
    }

    const float* xb = x   + ((size_t)b * 256 + sub * 8) * CS;
    float*       ob = out + ((size_t)b * 256 + sub * 8) * CS;

    #pragma unroll 2
    for (int ci = 0; ci < 8; ++ci) {
        const float* xp = xb + ci * CS + p;
        const bool unsafe = (b == 0 && sub == 0 && ci == 0) ||
                            (b == 3 && sub == 31 && ci == 7);
        float y = 0.f, ctr;
        if (!unsafe) {
            #pragma unroll
            for (int r = 0; r < 5; ++r) {
                const float* rp = xp + (r - 2) * 56;
                const f4a   v4 = *(const f4a*)(rp - 2);    // dx -2..+1
                const float s4 = rp[2];                    // dx +2
                if (r == 2) ctr = v4.z;
                y = fmaf(wq[r*5+0], v4.x, y);
                y = fmaf(wq[r*5+1], v4.y, y);
                y = fmaf(wq[r*5+2], v4.z, y);
                y = fmaf(wq[r*5+3], v4.w, y);
                y = fmaf(wq[r*5+4], s4,   y);
            }
        } else {
            ctr = xp[0];
            #pragma unroll
            for (int k = 0; k < 25; ++k) {
                const int dy = k / 5 - 2, dx = k % 5 - 2;
                const bool vr = (dy == -2) ? vm2 : (dy == -1) ? vm1 : (dy == 0) ? true
                              : (dy == 1) ? vp1 : vp2;
                const bool vc = (dx == -2) ? cv0 : (dx == -1) ? cv1 : (dx == 0) ? true
                              : (dx == 1) ? cv3 : cv4;
                const float xv = (vr && vc) ? xp[dy * 56 + dx] : 0.f;
                y = fmaf(wq[k], xv, y);
            }
        }
        ob[ci * CS + p] = ctr + g * y;
    }
}

extern "C" void kernel_launch(void* const* d_in, const int* in_sizes, int n_in,
                              void* d_out, int out_size, void* d_ws, size_t ws_size,
                              hipStream_t stream) {
    const float* x     = (const float*)d_in[0];
    const float* gamma = (const float*)d_in[1];
    float* out = (float*)d_out;
    float* dot = (float*)d_ws;                 // [4][13][3136]

    k_dot<<<392, 1024, 0, stream>>>(x, dot);
    k_fused<<<392, 1024, 0, stream>>>(x, dot, gamma, out);
}